// Round 1
// baseline (475.742 us; speedup 1.0000x reference)
//
#include <hip/hip_runtime.h>

constexpr int T = 168;
constexpr int P = 16;
constexpr int H = 24;
constexpr int G = 96;               // 4*H gates
constexpr int RPB = 2;              // rows per block
constexpr int BLOCK = RPB * G;      // 192 threads = 3 waves

__device__ __forceinline__ float rcp_f(float x) { return __builtin_amdgcn_rcpf(x); }
// sigmoid(x) = 1/(1+e^-x)
__device__ __forceinline__ float sigm_f(float x) { return rcp_f(1.f + __expf(-x)); }
// tanh(x) = 2/(1+e^-2x) - 1
__device__ __forceinline__ float tanh_fast(float x) {
    return fmaf(2.f, rcp_f(1.f + __expf(-2.f * x)), -1.f);
}

__global__ __launch_bounds__(BLOCK, 3)
void lstm2_fused(const float* __restrict__ x,
                 const float* __restrict__ Wih1, const float* __restrict__ Whh1,
                 const float* __restrict__ bih1, const float* __restrict__ bhh1,
                 const float* __restrict__ Wih2, const float* __restrict__ Whh2,
                 const float* __restrict__ bih2, const float* __restrict__ bhh2,
                 const float* __restrict__ W1, const float* __restrict__ b1,
                 const float* __restrict__ W2, const float* __restrict__ b2,
                 float* __restrict__ out)
{
    const int tid = threadIdx.x;
    const int lr  = tid / G;          // local row 0..1
    const int q   = tid - lr * G;     // gate row 0..95
    const int u   = q % H;            // hidden unit
    const int gt  = q / H;            // 0=i 1=f 2=g 3=o
    const int row = blockIdx.x * RPB + lr;

    __shared__ __align__(16) float h1s[RPB][H];
    __shared__ __align__(16) float th1s[RPB][H];
    __shared__ __align__(16) float h2s[RPB][H];
    __shared__ __align__(16) float gs[RPB][G];

    // ---- per-lane weights into registers (88 VGPRs) ----
    float wih1[P], whh1[H], wih2[H], whh2[H];
    {
        const float4* p = (const float4*)(Wih1 + q * P);
        #pragma unroll
        for (int k = 0; k < P / 4; ++k) {
            float4 v = p[k];
            wih1[4*k] = v.x; wih1[4*k+1] = v.y; wih1[4*k+2] = v.z; wih1[4*k+3] = v.w;
        }
    }
    {
        const float4* p = (const float4*)(Whh1 + q * H);
        #pragma unroll
        for (int k = 0; k < H / 4; ++k) {
            float4 v = p[k];
            whh1[4*k] = v.x; whh1[4*k+1] = v.y; whh1[4*k+2] = v.z; whh1[4*k+3] = v.w;
        }
    }
    {
        const float4* p = (const float4*)(Wih2 + q * H);
        #pragma unroll
        for (int k = 0; k < H / 4; ++k) {
            float4 v = p[k];
            wih2[4*k] = v.x; wih2[4*k+1] = v.y; wih2[4*k+2] = v.z; wih2[4*k+3] = v.w;
        }
    }
    {
        const float4* p = (const float4*)(Whh2 + q * H);
        #pragma unroll
        for (int k = 0; k < H / 4; ++k) {
            float4 v = p[k];
            whh2[4*k] = v.x; whh2[4*k+1] = v.y; whh2[4*k+2] = v.z; whh2[4*k+3] = v.w;
        }
    }
    const float bs1 = bih1[q] + bhh1[q];
    const float bs2 = bih2[q] + bhh2[q];

    // zero-init recurrent state (harness poisons memory with 0xAA)
    if (tid < RPB * H) {
        h1s[tid / H][tid % H] = 0.f;
        h2s[tid / H][tid % H] = 0.f;
    }
    float c1 = 0.f, c2 = 0.f;
    float a1 = 0.f, a2 = 0.f;

    // x(t=0) into registers
    const float4* xv = (const float4*)(x + (size_t)row * T * P);
    float xb[P];
    #pragma unroll
    for (int k = 0; k < 4; ++k) {
        float4 v = xv[k];
        xb[4*k] = v.x; xb[4*k+1] = v.y; xb[4*k+2] = v.z; xb[4*k+3] = v.w;
    }
    __syncthreads();

    for (int t = 0; t < T; ++t) {
        // ---- Phase 1: layer-1 gate pre-activation + activation ----
        float acc = bs1;
        #pragma unroll
        for (int k = 0; k < P; ++k) acc = fmaf(xb[k], wih1[k], acc);
        #pragma unroll
        for (int k = 0; k < H / 4; ++k) {
            float4 hv = ((const float4*)h1s[lr])[k];
            acc = fmaf(hv.x, whh1[4*k],   acc);
            acc = fmaf(hv.y, whh1[4*k+1], acc);
            acc = fmaf(hv.z, whh1[4*k+2], acc);
            acc = fmaf(hv.w, whh1[4*k+3], acc);
        }
        // prefetch x(t+1) after consuming xb (latency hidden across phases)
        if (t + 1 < T) {
            #pragma unroll
            for (int k = 0; k < 4; ++k) {
                float4 v = xv[(t + 1) * 4 + k];
                xb[4*k] = v.x; xb[4*k+1] = v.y; xb[4*k+2] = v.z; xb[4*k+3] = v.w;
            }
        }
        // unified activation: tanh for gt==2 via 2*sigmoid(2x)-1 (no divergence)
        {
            float px = (gt == 2) ? acc + acc : acc;
            float s  = sigm_f(px);
            a1 = (gt == 2) ? s + s - 1.f : s;
        }
        gs[lr][q] = a1;
        __syncthreads();

        // ---- Phase 2: layer-1 state update (lanes q<H; a1 is the i-gate here) ----
        if (q < H) {
            float fv = gs[lr][H + u];
            float gv = gs[lr][2 * H + u];
            float ov = gs[lr][3 * H + u];
            c1 = fmaf(fv, c1, a1 * gv);
            float h1v = ov * tanh_fast(c1);
            h1s[lr][u]  = h1v;
            th1s[lr][u] = tanh_fast(h1v);   // layer-2 input
        }
        __syncthreads();

        // ---- Phase 3: layer-2 gate ----
        acc = bs2;
        #pragma unroll
        for (int k = 0; k < H / 4; ++k) {
            float4 hv = ((const float4*)th1s[lr])[k];
            acc = fmaf(hv.x, wih2[4*k],   acc);
            acc = fmaf(hv.y, wih2[4*k+1], acc);
            acc = fmaf(hv.z, wih2[4*k+2], acc);
            acc = fmaf(hv.w, wih2[4*k+3], acc);
        }
        #pragma unroll
        for (int k = 0; k < H / 4; ++k) {
            float4 hv = ((const float4*)h2s[lr])[k];
            acc = fmaf(hv.x, whh2[4*k],   acc);
            acc = fmaf(hv.y, whh2[4*k+1], acc);
            acc = fmaf(hv.z, whh2[4*k+2], acc);
            acc = fmaf(hv.w, whh2[4*k+3], acc);
        }
        {
            float px = (gt == 2) ? acc + acc : acc;
            float s  = sigm_f(px);
            a2 = (gt == 2) ? s + s - 1.f : s;
        }
        gs[lr][q] = a2;
        __syncthreads();

        // ---- Phase 4: layer-2 state update ----
        if (q < H) {
            float fv = gs[lr][H + u];
            float gv = gs[lr][2 * H + u];
            float ov = gs[lr][3 * H + u];
            c2 = fmaf(fv, c2, a2 * gv);
            h2s[lr][u] = ov * tanh_fast(c2);
        }
        __syncthreads();
    }

    // ---- head: tanh -> fc1(relu, 16) -> fc2(24) ----
    if (q < H) th1s[lr][u] = tanh_fast(h2s[lr][u]);
    __syncthreads();
    if (q < 16) {
        float acc = b1[q];
        #pragma unroll
        for (int j = 0; j < H; ++j) acc = fmaf(th1s[lr][j], W1[q * H + j], acc);
        gs[lr][q] = fmaxf(acc, 0.f);
    }
    __syncthreads();
    if (q < H) {
        float acc = b2[q];
        #pragma unroll
        for (int j = 0; j < 16; ++j) acc = fmaf(gs[lr][j], W2[q * 16 + j], acc);
        out[(size_t)row * H + q] = acc;
    }
}

extern "C" void kernel_launch(void* const* d_in, const int* in_sizes, int n_in,
                              void* d_out, int out_size, void* d_ws, size_t ws_size,
                              hipStream_t stream)
{
    const float* x    = (const float*)d_in[0];
    const float* Wih1 = (const float*)d_in[1];
    const float* Whh1 = (const float*)d_in[2];
    const float* bih1 = (const float*)d_in[3];
    const float* bhh1 = (const float*)d_in[4];
    const float* Wih2 = (const float*)d_in[5];
    const float* Whh2 = (const float*)d_in[6];
    const float* bih2 = (const float*)d_in[7];
    const float* bhh2 = (const float*)d_in[8];
    const float* W1   = (const float*)d_in[9];
    const float* b1   = (const float*)d_in[10];
    const float* W2   = (const float*)d_in[11];
    const float* b2   = (const float*)d_in[12];
    float* out = (float*)d_out;

    const int B = 4096;
    dim3 grid(B / RPB), block(BLOCK);
    hipLaunchKernelGGL(lstm2_fused, grid, block, 0, stream,
                       x, Wih1, Whh1, bih1, bhh1, Wih2, Whh2, bih2, bhh2,
                       W1, b1, W2, b2, out);
}

// Round 2
// 448.659 us; speedup vs baseline: 1.0604x; 1.0604x over previous
//
#include <hip/hip_runtime.h>

constexpr int T = 168;
constexpr int P = 16;
constexpr int H = 24;

__device__ __forceinline__ float rcp_f(float x) { return __builtin_amdgcn_rcpf(x); }
__device__ __forceinline__ float sigm_f(float x) { return rcp_f(1.f + __expf(-x)); }
// tanh(x) = 2*sigmoid(2x) - 1
__device__ __forceinline__ float tanh_fast(float x) {
    return fmaf(2.f, rcp_f(1.f + __expf(-2.f * x)), -1.f);
}

// LDS write->read ordering within a single wave: DS ops from one wave execute
// in order; we only need the counter drained + a compiler reorder fence.
#define LDS_SYNC() asm volatile("s_waitcnt lgkmcnt(0)" ::: "memory")

// One row per 64-lane wave. Lane u in [0,24): gates {i, g} of unit u.
// Lane 24+u: gates {f, o}. Lanes 48..63 idle (duplicate lane 47, never store).
// No __syncthreads anywhere: all comms are intra-wave (shfl + wave-sync LDS).
__global__ __attribute__((amdgpu_flat_work_group_size(64, 64),
                          amdgpu_waves_per_eu(2, 2)))
void lstm2_wave(const float* __restrict__ x,
                const float* __restrict__ Wih1, const float* __restrict__ Whh1,
                const float* __restrict__ bih1, const float* __restrict__ bhh1,
                const float* __restrict__ Wih2, const float* __restrict__ Whh2,
                const float* __restrict__ bih2, const float* __restrict__ bhh2,
                const float* __restrict__ W1, const float* __restrict__ b1,
                const float* __restrict__ W2, const float* __restrict__ b2,
                float* __restrict__ out)
{
    const int lane = threadIdx.x;                 // 0..63
    const int s    = (lane < 48) ? lane : 47;     // clamp idle lanes onto valid rows
    const int u    = s % H;                       // unit 0..23
    const int half = s / H;                       // 0: {i,g}, 1: {f,o}
    const int q0   = half * H + u;                // i or f gate row
    const int q1   = (2 + half) * H + u;          // g or o gate row
    const int row  = blockIdx.x;

    // ---- weights into registers: 2*(16+24) + 2*(24+24) = 176 floats ----
    float wx0[P], wx1[P];         // Wih1 rows q0, q1
    float wh0[H], wh1[H];         // Whh1 rows q0, q1
    float vx0[H], vx1[H];         // Wih2 rows q0, q1
    float vh0[H], vh1[H];         // Whh2 rows q0, q1
    #pragma unroll
    for (int k = 0; k < P / 4; ++k) {
        float4 a = ((const float4*)(Wih1 + q0 * P))[k];
        float4 b = ((const float4*)(Wih1 + q1 * P))[k];
        wx0[4*k] = a.x; wx0[4*k+1] = a.y; wx0[4*k+2] = a.z; wx0[4*k+3] = a.w;
        wx1[4*k] = b.x; wx1[4*k+1] = b.y; wx1[4*k+2] = b.z; wx1[4*k+3] = b.w;
    }
    #pragma unroll
    for (int k = 0; k < H / 4; ++k) {
        float4 a = ((const float4*)(Whh1 + q0 * H))[k];
        float4 b = ((const float4*)(Whh1 + q1 * H))[k];
        wh0[4*k] = a.x; wh0[4*k+1] = a.y; wh0[4*k+2] = a.z; wh0[4*k+3] = a.w;
        wh1[4*k] = b.x; wh1[4*k+1] = b.y; wh1[4*k+2] = b.z; wh1[4*k+3] = b.w;
    }
    #pragma unroll
    for (int k = 0; k < H / 4; ++k) {
        float4 a = ((const float4*)(Wih2 + q0 * H))[k];
        float4 b = ((const float4*)(Wih2 + q1 * H))[k];
        vx0[4*k] = a.x; vx0[4*k+1] = a.y; vx0[4*k+2] = a.z; vx0[4*k+3] = a.w;
        vx1[4*k] = b.x; vx1[4*k+1] = b.y; vx1[4*k+2] = b.z; vx1[4*k+3] = b.w;
    }
    #pragma unroll
    for (int k = 0; k < H / 4; ++k) {
        float4 a = ((const float4*)(Whh2 + q0 * H))[k];
        float4 b = ((const float4*)(Whh2 + q1 * H))[k];
        vh0[4*k] = a.x; vh0[4*k+1] = a.y; vh0[4*k+2] = a.z; vh0[4*k+3] = a.w;
        vh1[4*k] = b.x; vh1[4*k+1] = b.y; vh1[4*k+2] = b.z; vh1[4*k+3] = b.w;
    }
    const float b10 = bih1[q0] + bhh1[q0];
    const float b11 = bih1[q1] + bhh1[q1];
    const float b20 = bih2[q0] + bhh2[q0];
    const float b21 = bih2[q1] + bhh2[q1];

    __shared__ __align__(16) float h1s[32];   // layer-1 h
    __shared__ __align__(16) float t1s[32];   // tanh(layer-1 h) = layer-2 input
    __shared__ __align__(16) float h2s[32];   // layer-2 h

    if (lane < H) { h1s[lane] = 0.f; t1s[lane] = 0.f; h2s[lane] = 0.f; }
    LDS_SYNC();

    const float* __restrict__ xrow = x + (size_t)row * T * P;  // wave-uniform

    float c1 = 0.f, c2 = 0.f;

    for (int t = 0; t < T; ++t) {
        // ---- layer-1 gates ----
        float g0 = b10, g1 = b11;
        #pragma unroll
        for (int k = 0; k < P; ++k) {
            float xv = xrow[t * P + k];              // uniform -> scalar load
            g0 = fmaf(xv, wx0[k], g0);
            g1 = fmaf(xv, wx1[k], g1);
        }
        #pragma unroll
        for (int k = 0; k < H / 4; ++k) {
            float4 hv = ((const float4*)h1s)[k];
            g0 = fmaf(hv.x, wh0[4*k],   g0);  g1 = fmaf(hv.x, wh1[4*k],   g1);
            g0 = fmaf(hv.y, wh0[4*k+1], g0);  g1 = fmaf(hv.y, wh1[4*k+1], g1);
            g0 = fmaf(hv.z, wh0[4*k+2], g0);  g1 = fmaf(hv.z, wh1[4*k+2], g1);
            g0 = fmaf(hv.w, wh0[4*k+3], g0);  g1 = fmaf(hv.w, wh1[4*k+3], g1);
        }
        // activations: a0 = sigmoid(g0) [i or f]; a1 = tanh(g1) [g] on half 0,
        // sigmoid(g1) [o] on half 1 — branch-free via 2*sigm(2x)-1
        float a0 = sigm_f(g0);
        float px = (half == 0) ? g1 + g1 : g1;
        float sv = sigm_f(px);
        float a1 = (half == 0) ? sv + sv - 1.f : sv;
        // exchange: lane u pulls (f,o) from lane 24+u
        float fa = __shfl(a0, lane + 24);
        float oa = __shfl(a1, lane + 24);
        // state update (valid on lanes < 24; upper lanes compute garbage, unused)
        c1 = fmaf(fa, c1, a0 * a1);                  // f*c + i*tanh(g)
        float h1 = oa * tanh_fast(c1);
        float th1 = tanh_fast(h1);
        if (lane < H) { h1s[lane] = h1; t1s[lane] = th1; }
        LDS_SYNC();

        // ---- layer-2 gates ----
        float g2 = b20, g3 = b21;
        #pragma unroll
        for (int k = 0; k < H / 4; ++k) {
            float4 tv = ((const float4*)t1s)[k];
            g2 = fmaf(tv.x, vx0[4*k],   g2);  g3 = fmaf(tv.x, vx1[4*k],   g3);
            g2 = fmaf(tv.y, vx0[4*k+1], g2);  g3 = fmaf(tv.y, vx1[4*k+1], g3);
            g2 = fmaf(tv.z, vx0[4*k+2], g2);  g3 = fmaf(tv.z, vx1[4*k+2], g3);
            g2 = fmaf(tv.w, vx0[4*k+3], g2);  g3 = fmaf(tv.w, vx1[4*k+3], g3);
        }
        #pragma unroll
        for (int k = 0; k < H / 4; ++k) {
            float4 hv = ((const float4*)h2s)[k];
            g2 = fmaf(hv.x, vh0[4*k],   g2);  g3 = fmaf(hv.x, vh1[4*k],   g3);
            g2 = fmaf(hv.y, vh0[4*k+1], g2);  g3 = fmaf(hv.y, vh1[4*k+1], g3);
            g2 = fmaf(hv.z, vh0[4*k+2], g2);  g3 = fmaf(hv.z, vh1[4*k+2], g3);
            g2 = fmaf(hv.w, vh0[4*k+3], g2);  g3 = fmaf(hv.w, vh1[4*k+3], g3);
        }
        float a2 = sigm_f(g2);
        float py = (half == 0) ? g3 + g3 : g3;
        float sw = sigm_f(py);
        float a3 = (half == 0) ? sw + sw - 1.f : sw;
        float fb = __shfl(a2, lane + 24);
        float ob = __shfl(a3, lane + 24);
        c2 = fmaf(fb, c2, a2 * a3);
        float h2 = ob * tanh_fast(c2);
        if (lane < H) h2s[lane] = h2;
        LDS_SYNC();
    }

    // ---- head: tanh -> fc1(16, relu) -> fc2(24) ----
    if (lane < H) t1s[lane] = tanh_fast(h2s[lane]);
    LDS_SYNC();
    if (lane < 16) {
        float acc = b1[lane];
        #pragma unroll
        for (int j = 0; j < H; ++j) acc = fmaf(t1s[j], W1[lane * H + j], acc);
        h1s[lane] = fmaxf(acc, 0.f);                 // reuse h1s as fc1 output
    }
    LDS_SYNC();
    if (lane < H) {
        float acc = b2[lane];
        #pragma unroll
        for (int j = 0; j < 16; ++j) acc = fmaf(h1s[j], W2[lane * 16 + j], acc);
        out[(size_t)row * H + lane] = acc;
    }
}

extern "C" void kernel_launch(void* const* d_in, const int* in_sizes, int n_in,
                              void* d_out, int out_size, void* d_ws, size_t ws_size,
                              hipStream_t stream)
{
    const float* x    = (const float*)d_in[0];
    const float* Wih1 = (const float*)d_in[1];
    const float* Whh1 = (const float*)d_in[2];
    const float* bih1 = (const float*)d_in[3];
    const float* bhh1 = (const float*)d_in[4];
    const float* Wih2 = (const float*)d_in[5];
    const float* Whh2 = (const float*)d_in[6];
    const float* bih2 = (const float*)d_in[7];
    const float* bhh2 = (const float*)d_in[8];
    const float* W1   = (const float*)d_in[9];
    const float* b1   = (const float*)d_in[10];
    const float* W2   = (const float*)d_in[11];
    const float* b2   = (const float*)d_in[12];
    float* out = (float*)d_out;

    const int B = in_sizes[0] / (T * P);             // 4096
    hipLaunchKernelGGL(lstm2_wave, dim3(B), dim3(64), 0, stream,
                       x, Wih1, Whh1, bih1, bhh1, Wih2, Whh2, bih2, bhh2,
                       W1, b1, W2, b2, out);
}